// Round 7
// baseline (1097.138 us; speedup 1.0000x reference)
//
#include <hip/hip_runtime.h>
#include <math.h>

// DrugGraphConv: 5000 graphs x 100 nodes x 400 edges, 5 TAGConv(K=2) layers
// DIMS = [74,70,65,60,55,37], gated softmax pooling per graph.
//
// R9 (732us): dense on MFMA bf16 hi/lo split (AhBh+AhBl+AlBh).
// R10 (701us): buffer-flip layer output, x dwordx4 staging.
// R11 (690us): dual-chunk propagate (+55% bank conflicts ate most of it).
// R12 (713us): 1024-thr blocks -> Occ 88%, BUT __launch_bounds__(1024,8)
// capped VGPR at 32 -> scratch spills (WRITE_SIZE 859KB -> 77MB). Empirical
// semantics: 2nd launch_bounds arg = min BLOCKS per CU (CUDA-style):
// (512,4)->cap 64, (1024,8)->cap 32. NOT waves/EU.
//
// R13: keep 1024-thr/2-block structure; __launch_bounds__(1024,2) -> VGPR
// cap 64 (natural use ~50, no spill). Revert propagate to single-chunk
// (dual needs ~58 live regs, too tight at 64; also restores lower bank
// conflicts). Weighted shares kept: waves 0-13 5%, waves 14-15 15%.

typedef __attribute__((ext_vector_type(8))) short bf16x8;
typedef __attribute__((ext_vector_type(4))) float f32x4;

constexpr int NODES  = 100;
constexpr int EDGES  = 400;
constexpr int STRIDE = 76;     // floats per LDS row (mult of 4)
constexpr int NTHR   = 1024;

// packed W frags: per layer, per (b,kt,nt): 64 lanes x (8 bf16 hi + 8 bf16 lo)
// = 2048B per frag-tile. tiles: L0 3*3*5=45, L1 45, L2 36, L3 24, L4 18.
// u32 offsets: 0, 23040, 46080, 64512, 76800; total 86016 u32 = 344KB.
__device__ __align__(16) unsigned g_packW[86016];

struct __align__(16) Smem {
    float bufA[NODES * STRIDE];        // 30,400 B (pool scratch at epilogue)
    float bufB[NODES * STRIDE];        // 30,400 B
    float csr_val[EDGES];              //  1,600 B (nrm[src] per CSR slot)
    unsigned short csr_src[EDGES];     //    800 B
    int   row_start[NODES + 1];        //    404 B
    int   cntg[NODES];                 //    400 B (cnt setup, gate after)
    float nrm[NODES];                  //    400 B  => 64,404 B (2 blocks/CU)
};

union FragU { unsigned u[4]; uint4 q; bf16x8 s; };

// truncation hi/lo bf16 split of a pair, packed little-endian (a -> low16).
__device__ __forceinline__ void split_pair(float a, float b,
                                           unsigned& h, unsigned& l) {
    unsigned ua = __float_as_uint(a), ub = __float_as_uint(b);
    unsigned ha = ua & 0xFFFF0000u,  hb = ub & 0xFFFF0000u;
    h = (ua >> 16) | hb;
    float ra = a - __uint_as_float(ha);
    float rb = b - __uint_as_float(hb);
    l = (__float_as_uint(ra) >> 16) | (__float_as_uint(rb) & 0xFFFF0000u);
}

// ---------------- repack kernel: W -> frag-ready bf16 hi/lo ----------------
template<int D_IN, int D_OUT, int KT, int NT, int WOFF_U32>
__device__ __forceinline__ void repack_layer(const float* __restrict__ W, int idx) {
    constexpr int TILES = 3 * KT * NT;
    if (idx >= TILES * 64) return;
    int lane = idx & 63, tile = idx >> 6;
    int nt = tile % NT;
    int kt = (tile / NT) % KT;
    int b  = tile / (NT * KT);
    int col = nt * 16 + (lane & 15);
    int kg  = (lane >> 4) << 2;
    float v[8];
#pragma unroll
    for (int i = 0; i < 8; ++i) {
        int k = kt * 32 + ((i >= 4) ? 16 : 0) + kg + (i & 3);
        float f = 0.f;
        if (k < D_IN && col < D_OUT) f = W[(b * D_IN + k) * D_OUT + col];
        v[i] = f;
    }
    unsigned hu[4], lu[4];
#pragma unroll
    for (int p = 0; p < 4; ++p) split_pair(v[2*p], v[2*p+1], hu[p], lu[p]);
    unsigned* dst = g_packW + WOFF_U32 + (tile * 64 + lane) * 8;
    *(uint4*)(dst)     = make_uint4(hu[0], hu[1], hu[2], hu[3]);
    *(uint4*)(dst + 4) = make_uint4(lu[0], lu[1], lu[2], lu[3]);
}

__global__ void repack_kernel(const float* __restrict__ W0, const float* __restrict__ W1,
                              const float* __restrict__ W2, const float* __restrict__ W3,
                              const float* __restrict__ W4) {
    int idx = blockIdx.x * 256 + threadIdx.x;
    switch (blockIdx.y) {
    case 0: repack_layer<74, 70, 3, 5,     0>(W0, idx); break;
    case 1: repack_layer<70, 65, 3, 5, 23040>(W1, idx); break;
    case 2: repack_layer<65, 60, 3, 4, 46080>(W2, idx); break;
    case 3: repack_layer<60, 55, 2, 4, 64512>(W3, idx); break;
    case 4: repack_layer<55, 37, 2, 3, 76800>(W4, idx); break;
    }
}

// ---------------- propagation (CSR gather, fp32 VALU, single-chunk) --------
// out[n][:] = nrm[n] * sum_{e: dst==n} csr_val[e] * in[src_e][:]
// Weighted wave shares: cumW(w) = 5w for w<=14, 70+15(w-14) for w>14.
template<int D_IN>
__device__ __forceinline__ void propagate(const float* __restrict__ in,
                                          float* __restrict__ outb,
                                          const unsigned short* __restrict__ csr_src,
                                          const float* __restrict__ csr_val,
                                          const int* __restrict__ row_start,
                                          const float* __restrict__ nrm,
                                          int wave, int lane)
{
    constexpr int CH = (D_IN + 3) / 4;            // valid float4 chunks
    constexpr int T  = NODES * CH;                // total tasks
    constexpr int R4 = STRIDE / 4;                // 19 float4 per row
    const float4* __restrict__ in4 = (const float4*)in;
    float4* __restrict__ out4 = (float4*)outb;

    const int cw0 = (wave <= 14) ? 5 * wave : 70 + 15 * (wave - 14);
    const int w1  = wave + 1;
    const int cw1 = (w1 <= 14) ? 5 * w1 : 70 + 15 * (w1 - 14);
    const int lo = (T * cw0) / 100;               // uniform per wave
    const int hi = (T * cw1) / 100;

    for (int t = lo + lane; t < hi; t += 64) {
        int n = t / CH;                           // const-divisor mulshift
        int c = t - n * CH;
        int beg = row_start[n], end = row_start[n + 1];
        float ax = 0.f, ay = 0.f, az = 0.f, aw = 0.f;
        int e = beg;
        for (; e + 3 < end; e += 4) {
            int   s0 = csr_src[e],     s1 = csr_src[e + 1];
            int   s2 = csr_src[e + 2], s3 = csr_src[e + 3];
            float c0 = csr_val[e],     c1 = csr_val[e + 1];
            float c2 = csr_val[e + 2], c3 = csr_val[e + 3];
            float4 v0 = in4[s0 * R4 + c];
            float4 v1 = in4[s1 * R4 + c];
            float4 v2 = in4[s2 * R4 + c];
            float4 v3 = in4[s3 * R4 + c];
            ax = fmaf(c0, v0.x, ax); ay = fmaf(c0, v0.y, ay);
            az = fmaf(c0, v0.z, az); aw = fmaf(c0, v0.w, aw);
            ax = fmaf(c1, v1.x, ax); ay = fmaf(c1, v1.y, ay);
            az = fmaf(c1, v1.z, az); aw = fmaf(c1, v1.w, aw);
            ax = fmaf(c2, v2.x, ax); ay = fmaf(c2, v2.y, ay);
            az = fmaf(c2, v2.z, az); aw = fmaf(c2, v2.w, aw);
            ax = fmaf(c3, v3.x, ax); ay = fmaf(c3, v3.y, ay);
            az = fmaf(c3, v3.z, az); aw = fmaf(c3, v3.w, aw);
        }
        for (; e < end; ++e) {
            int s = csr_src[e];
            float sc = csr_val[e];
            float4 v = in4[s * R4 + c];
            ax = fmaf(sc, v.x, ax); ay = fmaf(sc, v.y, ay);
            az = fmaf(sc, v.z, az); aw = fmaf(sc, v.w, aw);
        }
        float sn = nrm[n];
        float4 o = { ax * sn, ay * sn, az * sn, aw * sn };
        out4[n * R4 + c] = o;
    }
}

// ---------------- one feats-block of the dense matmul on MFMA --------------
// wave handles m-tile mt and n-tiles {nh, nh+2, ...}; acc has (NT+1)/2 slots.
template<int D_IN, int D_OUT, int KT, int NT, int WOFF_U32>
__device__ __forceinline__ void dense_block(const float* __restrict__ buf, int b,
                                            int mt, int nh, int lane,
                                            f32x4 (&acc)[(NT + 1) / 2]) {
    constexpr int NTH = (NT + 1) / 2;
    int row = mt * 16 + (lane & 15);
    row = row > NODES - 1 ? NODES - 1 : row;   // clamped rows masked at store
    const float* __restrict__ hrow = buf + row * STRIDE;
    const int kg = (lane >> 4) << 2;
    const uint4* __restrict__ wb =
        (const uint4*)(g_packW + WOFF_U32) + b * (KT * NT * 128) + lane * 2;
#pragma unroll
    for (int kt = 0; kt < KT; ++kt) {
        // clamp so reads stay inside the row's 76 valid floats (finite data;
        // k>=D_IN lanes are killed by zeroed W rows, value irrelevant).
        int o0 = kt * 32 + kg;      if (o0 > 72) o0 = 72;
        int o1 = kt * 32 + 16 + kg; if (o1 > 72) o1 = 72;
        const float4 f0 = *(const float4*)(hrow + o0);   // ds_read_b128
        const float4 f1 = *(const float4*)(hrow + o1);
        FragU Ah, Al;
        split_pair(f0.x, f0.y, Ah.u[0], Al.u[0]);
        split_pair(f0.z, f0.w, Ah.u[1], Al.u[1]);
        split_pair(f1.x, f1.y, Ah.u[2], Al.u[2]);
        split_pair(f1.z, f1.w, Ah.u[3], Al.u[3]);
#pragma unroll
        for (int i = 0; i < NTH; ++i) {
            int nt = nh + 2 * i;                 // wave-uniform guard
            if (nt < NT) {
                const uint4* __restrict__ wl = wb + (kt * NT + nt) * 128;
                FragU Bh, Bl;
                Bh.q = wl[0];        // global_load_dwordx4, L1/L2-resident
                Bl.q = wl[1];
                acc[i] = __builtin_amdgcn_mfma_f32_16x16x32_bf16(Ah.s, Bh.s, acc[i], 0, 0, 0);
                acc[i] = __builtin_amdgcn_mfma_f32_16x16x32_bf16(Ah.s, Bl.s, acc[i], 0, 0, 0);
                acc[i] = __builtin_amdgcn_mfma_f32_16x16x32_bf16(Al.s, Bh.s, acc[i], 0, 0, 0);
            }
        }
    }
}

// ---------------- one TAGConv layer (src S, output -> T) -------------------
// Phase 1: gblock(S,0) || prop(S->T); B. Phase 2: gblock(T,1) || prop(T->S); B.
// Phase 3: gblock(S,2); store ReLU -> T (T dead after phase 2; nothing reads
// T in phase 3, so no barrier between gblock2 and store). B. Next src = T.
// Stale cols >= D_OUT in T are killed by zero-padded W / never read by gate.
template<int D_IN, int D_OUT, int KT, int NT, int WOFF_U32>
__device__ __forceinline__ void tag_layer(Smem& sm,
                                          float* __restrict__ S,
                                          float* __restrict__ T,
                                          const float* __restrict__ Bv,
                                          int tid)
{
    constexpr int NTH = (NT + 1) / 2;
    const int wave  = __builtin_amdgcn_readfirstlane(tid >> 6); // uniform
    const int lane  = tid & 63;
    const int mt    = wave >> 1;
    const int nh    = wave & 1;
    const bool m_act = wave < 14;     // 7 m-tiles x 2 n-halves

    f32x4 acc[NTH];
#pragma unroll
    for (int i = 0; i < NTH; ++i) acc[i] = (f32x4)(0.f);

    if (m_act) dense_block<D_IN, D_OUT, KT, NT, WOFF_U32>(S, 0, mt, nh, lane, acc);
    propagate<D_IN>(S, T, sm.csr_src, sm.csr_val, sm.row_start, sm.nrm, wave, lane);
    __syncthreads();
    if (m_act) dense_block<D_IN, D_OUT, KT, NT, WOFF_U32>(T, 1, mt, nh, lane, acc);
    propagate<D_IN>(T, S, sm.csr_src, sm.csr_val, sm.row_start, sm.nrm, wave, lane);
    __syncthreads();
    if (m_act) {
        dense_block<D_IN, D_OUT, KT, NT, WOFF_U32>(S, 2, mt, nh, lane, acc);
        // C/D layout (verified): col = lane&15, row_in_tile = (lane>>4)*4 + r
#pragma unroll
        for (int i = 0; i < NTH; ++i) {
            int nt = nh + 2 * i;
            if (nt < NT) {
                int col = nt * 16 + (lane & 15);
                if (col < D_OUT) {
                    float bias = Bv[col];
#pragma unroll
                    for (int r = 0; r < 4; ++r) {
                        int row = mt * 16 + ((lane >> 4) << 2) + r;
                        if (row < NODES)
                            T[row * STRIDE + col] = fmaxf(acc[i][r] + bias, 0.f);
                    }
                }
            }
        }
    }
    __syncthreads();
}

// 2nd arg = min BLOCKS per CU (empirical, R12): 2 blocks x 16 waves = 32
// waves/CU = 8/SIMD -> VGPR cap 64. (8 here caused cap 32 + scratch spills.)
__global__ __launch_bounds__(NTHR, 2)
void drug_graph_conv_kernel(
    const float* __restrict__ x,
    const int*   __restrict__ src,
    const int*   __restrict__ dst,
    const float* __restrict__ b0, const float* __restrict__ b1,
    const float* __restrict__ b2, const float* __restrict__ b3,
    const float* __restrict__ b4,
    const float* __restrict__ gate_w, const float* __restrict__ gate_b,
    float* __restrict__ out)
{
    __shared__ Smem sm;
    const int g     = blockIdx.x;
    const int tid   = threadIdx.x;
    const int nbase = g * NODES;

    // ---- stage x (100 x 74) into bufA at stride 76, dwordx4 loads ----
    {
        const float4* __restrict__ x4 = (const float4*)(x + (size_t)nbase * 74);
        for (int t = tid; t < NODES * 74 / 4; t += NTHR) {   // 1850
            float4 v = x4[t];
            int idx = 4 * t;
#pragma unroll
            for (int k = 0; k < 4; ++k) {
                int ik = idx + k;
                int n  = ik / 74;
                int d  = ik - n * 74;
                float val = (k == 0) ? v.x : (k == 1) ? v.y : (k == 2) ? v.z : v.w;
                sm.bufA[n * STRIDE + d] = val;
            }
        }
    }
    for (int t = tid; t < NODES * 2; t += NTHR) {
        int n = t >> 1;
        sm.bufA[n * STRIDE + 74 + (t & 1)] = 0.f;
    }

    // ---- degree count ----
    if (tid < NODES) sm.cntg[tid] = 0;
    __syncthreads();
    int es = 0, ed = 0;
    const bool ethr = tid < EDGES;
    if (ethr) {
        es = src[g * EDGES + tid] - nbase;
        ed = dst[g * EDGES + tid] - nbase;
        atomicAdd(&sm.cntg[ed], 1);
    }
    __syncthreads();

    // ---- norm + CSR row offsets (wave-0 shuffle scan over 100 degrees) ----
    if (tid < NODES) sm.nrm[tid] = rsqrtf((float)max(sm.cntg[tid], 1));
    if (tid < 64) {
        int v1 = (tid < NODES) ? sm.cntg[tid] : 0;
        int l2 = tid + 64;
        int v2 = (l2 < NODES) ? sm.cntg[l2] : 0;
        int s1 = v1;
#pragma unroll
        for (int d = 1; d < 64; d <<= 1) {
            int t2 = __shfl_up(s1, d, 64);
            if (tid >= d) s1 += t2;
        }
        int tot1 = __shfl(s1, 63, 64);
        int s2 = v2;
#pragma unroll
        for (int d = 1; d < 64; d <<= 1) {
            int t2 = __shfl_up(s2, d, 64);
            if (tid >= d) s2 += t2;
        }
        s2 += tot1;
        if (tid == 0) sm.row_start[0] = 0;
        sm.row_start[tid + 1] = s1;
        if (l2 < NODES) sm.row_start[l2 + 1] = s2;
    }
    __syncthreads();
    if (tid < NODES) sm.cntg[tid] = 0;   // reuse as CSR fill cursor
    __syncthreads();
    if (ethr) {
        int pos = atomicAdd(&sm.cntg[ed], 1);
        int slot = sm.row_start[ed] + pos;
        sm.csr_src[slot] = (unsigned short)es;
        sm.csr_val[slot] = sm.nrm[es];
    }
    __syncthreads();

    // ---- 5 TAGConv layers (MFMA dense), src/dst buffers alternate ----
    tag_layer<74, 70, 3, 5,     0>(sm, sm.bufA, sm.bufB, b0, tid);
    tag_layer<70, 65, 3, 5, 23040>(sm, sm.bufB, sm.bufA, b1, tid);
    tag_layer<65, 60, 3, 4, 46080>(sm, sm.bufA, sm.bufB, b2, tid);
    tag_layer<60, 55, 2, 4, 64512>(sm, sm.bufB, sm.bufA, b3, tid);
    tag_layer<55, 37, 2, 3, 76800>(sm, sm.bufA, sm.bufB, b4, tid);
    // final h: 100 x 37 in bufB, stride 76. bufA is dead -> pool scratch.

    // ---- gate + softmax + pool (gate stored in cntg as float) ----
    float* gate = (float*)sm.cntg;
    if (tid < NODES) {
        float s = gate_b[0];
#pragma unroll
        for (int k = 0; k < 37; ++k)
            s = fmaf(sm.bufB[tid * STRIDE + k], gate_w[k], s);
        gate[tid] = s;
    }
    __syncthreads();
    if (tid < 64) {
        float v1 = (tid < NODES) ? gate[tid] : -INFINITY;
        float v2 = (tid + 64 < NODES) ? gate[tid + 64] : -INFINITY;
        float m = fmaxf(v1, v2);
#pragma unroll
        for (int d = 32; d; d >>= 1) m = fmaxf(m, __shfl_xor(m, d, 64));
        float e1 = (tid < NODES) ? __expf(v1 - m) : 0.f;
        float e2 = (tid + 64 < NODES) ? __expf(v2 - m) : 0.f;
        float z = e1 + e2;
#pragma unroll
        for (int d = 32; d; d >>= 1) z += __shfl_xor(z, d, 64);
        float inv = 1.f / z;
        if (tid < NODES) gate[tid] = e1 * inv;
        if (tid + 64 < NODES) gate[tid + 64] = e2 * inv;
    }
    __syncthreads();

    // ---- parallel pool: 16 waves x 37 cols, partials in bufA scratch ----
    {
        const int w = tid >> 6, l = tid & 63;
        if (l < 37) {
            float p = 0.f;
            for (int n = w; n < NODES; n += 16)
                p = fmaf(gate[n], sm.bufB[n * STRIDE + l], p);
            sm.bufA[w * 37 + l] = p;
        }
    }
    __syncthreads();
    if (tid < 37) {
        float p = 0.f;
#pragma unroll
        for (int w = 0; w < 16; ++w) p += sm.bufA[w * 37 + tid];
        out[g * 37 + tid] = p;
    }
}

extern "C" void kernel_launch(void* const* d_in, const int* in_sizes, int n_in,
                              void* d_out, int out_size, void* d_ws, size_t ws_size,
                              hipStream_t stream) {
    const float* x   = (const float*)d_in[0];
    const int*   src = (const int*)  d_in[1];
    const int*   dst = (const int*)  d_in[2];
    // d_in[3] = graph_ids (implicit: node / 100) -- unused
    const float* W0 = (const float*)d_in[4];  const float* b0 = (const float*)d_in[5];
    const float* W1 = (const float*)d_in[6];  const float* b1 = (const float*)d_in[7];
    const float* W2 = (const float*)d_in[8];  const float* b2 = (const float*)d_in[9];
    const float* W3 = (const float*)d_in[10]; const float* b3 = (const float*)d_in[11];
    const float* W4 = (const float*)d_in[12]; const float* b4 = (const float*)d_in[13];
    const float* gw = (const float*)d_in[14]; const float* gb = (const float*)d_in[15];
    float* out = (float*)d_out;

    // repack W into MFMA frag layout (max layer 45 tiles * 64 = 2880 thr)
    dim3 rg(12, 5, 1);
    repack_kernel<<<rg, 256, 0, stream>>>(W0, W1, W2, W3, W4);

    drug_graph_conv_kernel<<<5000, NTHR, 0, stream>>>(
        x, src, dst, b0, b1, b2, b3, b4, gw, gb, out);
}

// Round 8
// 807.605 us; speedup vs baseline: 1.3585x; 1.3585x over previous
//
#include <hip/hip_runtime.h>
#include <math.h>

// DrugGraphConv: 5000 graphs x 100 nodes x 400 edges, 5 TAGConv(K=2) layers
// DIMS = [74,70,65,60,55,37], gated softmax pooling per graph.
//
// R9 (732us): dense on MFMA bf16 hi/lo split (AhBh+AhBl+AlBh).
// R10 (701us): buffer-flip layer output, x dwordx4 staging, full kt unroll.
// R11 (690us, BEST): dual-chunk propagate + weighted wave shares.
// R12 (713us): 1024-thr, Occ 88% but launch_bounds(1024,8) -> VGPR 32 + spills.
// R13 (1007us): 1024-thr spill-free but 2nd block lost co-residency (AGPR
// total > 64/lane; 16-wave workgroup = all-or-nothing) AND 1024-thr barrier
// domain is intrinsically worse than 2x512 async blocks. 1024-thr is dead.
//
// R14: R11 verbatim + __launch_bounds__(512,2) (VGPR cap 128, was 64).
// R8/R10's unrolls folded to a 52-VGPR minimal schedule BECAUSE the (512,4)
// budget forbade keeping unrolled loads in flight. Co-residency only needs
// VGPR<=128 (16 waves/CU, LDS-bound at 2 blocks). With cap 128 the scheduler
// can hoist next-kt ds_read/B-frag loads under current-kt MFMAs.

typedef __attribute__((ext_vector_type(8))) short bf16x8;
typedef __attribute__((ext_vector_type(4))) float f32x4;

constexpr int NODES  = 100;
constexpr int EDGES  = 400;
constexpr int STRIDE = 76;     // floats per LDS row (mult of 4)
constexpr int NTHR   = 512;

// packed W frags: per layer, per (b,kt,nt): 64 lanes x (8 bf16 hi + 8 bf16 lo)
// = 2048B per frag-tile. tiles: L0 3*3*5=45, L1 45, L2 36, L3 24, L4 18.
// u32 offsets: 0, 23040, 46080, 64512, 76800; total 86016 u32 = 344KB.
__device__ __align__(16) unsigned g_packW[86016];

struct __align__(16) Smem {
    float bufA[NODES * STRIDE];        // 30,400 B
    float bufB[NODES * STRIDE];        // 30,400 B
    float csr_val[EDGES];              //  1,600 B (nrm[src]; pool scratch later)
    unsigned short csr_src[EDGES];     //    800 B
    int   row_start[NODES + 1];        //    404 B
    int   cntg[NODES];                 //    400 B (cnt setup, gate after)
    float nrm[NODES];                  //    400 B  => 64,404 B (2 blocks/CU)
};

union FragU { unsigned u[4]; uint4 q; bf16x8 s; };

// truncation hi/lo bf16 split of a pair, packed little-endian (a -> low16).
__device__ __forceinline__ void split_pair(float a, float b,
                                           unsigned& h, unsigned& l) {
    unsigned ua = __float_as_uint(a), ub = __float_as_uint(b);
    unsigned ha = ua & 0xFFFF0000u,  hb = ub & 0xFFFF0000u;
    h = (ua >> 16) | hb;
    float ra = a - __uint_as_float(ha);
    float rb = b - __uint_as_float(hb);
    l = (__float_as_uint(ra) >> 16) | (__float_as_uint(rb) & 0xFFFF0000u);
}

// ---------------- repack kernel: W -> frag-ready bf16 hi/lo ----------------
template<int D_IN, int D_OUT, int KT, int NT, int WOFF_U32>
__device__ __forceinline__ void repack_layer(const float* __restrict__ W, int idx) {
    constexpr int TILES = 3 * KT * NT;
    if (idx >= TILES * 64) return;
    int lane = idx & 63, tile = idx >> 6;
    int nt = tile % NT;
    int kt = (tile / NT) % KT;
    int b  = tile / (NT * KT);
    int col = nt * 16 + (lane & 15);
    int kg  = (lane >> 4) << 2;
    float v[8];
#pragma unroll
    for (int i = 0; i < 8; ++i) {
        int k = kt * 32 + ((i >= 4) ? 16 : 0) + kg + (i & 3);
        float f = 0.f;
        if (k < D_IN && col < D_OUT) f = W[(b * D_IN + k) * D_OUT + col];
        v[i] = f;
    }
    unsigned hu[4], lu[4];
#pragma unroll
    for (int p = 0; p < 4; ++p) split_pair(v[2*p], v[2*p+1], hu[p], lu[p]);
    unsigned* dst = g_packW + WOFF_U32 + (tile * 64 + lane) * 8;
    *(uint4*)(dst)     = make_uint4(hu[0], hu[1], hu[2], hu[3]);
    *(uint4*)(dst + 4) = make_uint4(lu[0], lu[1], lu[2], lu[3]);
}

__global__ void repack_kernel(const float* __restrict__ W0, const float* __restrict__ W1,
                              const float* __restrict__ W2, const float* __restrict__ W3,
                              const float* __restrict__ W4) {
    int idx = blockIdx.x * 256 + threadIdx.x;
    switch (blockIdx.y) {
    case 0: repack_layer<74, 70, 3, 5,     0>(W0, idx); break;
    case 1: repack_layer<70, 65, 3, 5, 23040>(W1, idx); break;
    case 2: repack_layer<65, 60, 3, 4, 46080>(W2, idx); break;
    case 3: repack_layer<60, 55, 2, 4, 64512>(W3, idx); break;
    case 4: repack_layer<55, 37, 2, 3, 76800>(W4, idx); break;
    }
}

// ---------------- propagation (CSR gather, fp32 VALU) ----------------------
// out[n][:] = nrm[n] * sum_{e: dst==n} csr_val[e] * in[src_e][:]
// Dual-chunk tasks + weighted wave shares [6x7,14]/56.
template<int D_IN>
__device__ __forceinline__ void propagate(const float* __restrict__ in,
                                          float* __restrict__ outb,
                                          const unsigned short* __restrict__ csr_src,
                                          const float* __restrict__ csr_val,
                                          const int* __restrict__ row_start,
                                          const float* __restrict__ nrm,
                                          int wave, int lane)
{
    constexpr int CH = (D_IN + 3) / 4;            // valid float4 chunks
    constexpr int PR = (CH + 1) / 2;              // chunk-pairs per node
    constexpr int T  = NODES * PR;                // total tasks
    constexpr int R4 = STRIDE / 4;                // 19 float4 per row
    const float4* __restrict__ in4 = (const float4*)in;
    float4* __restrict__ out4 = (float4*)outb;

    // weighted contiguous partition: weights [6,6,6,6,6,6,6,14]/56
    const int lo = (T * (6 * wave)) / 56;                       // uniform
    const int hi = (wave == 7) ? T : (T * (6 * (wave + 1))) / 56;

    for (int t = lo + lane; t < hi; t += 64) {
        int n = t / PR;                           // const-divisor mulshift
        int p = t - n * PR;
        int c0 = 2 * p;
        int c1 = c0 + 1;
        bool has2 = (c1 < CH);                    // last pair of odd-CH nodes
        int c1r = has2 ? c1 : c0;                 // safe read index
        int beg = row_start[n], end = row_start[n + 1];
        float ax0 = 0.f, ay0 = 0.f, az0 = 0.f, aw0 = 0.f;
        float ax1 = 0.f, ay1 = 0.f, az1 = 0.f, aw1 = 0.f;
        int e = beg;
        for (; e + 3 < end; e += 4) {
            int   s0 = csr_src[e],     s1 = csr_src[e + 1];
            int   s2 = csr_src[e + 2], s3 = csr_src[e + 3];
            float q0 = csr_val[e],     q1 = csr_val[e + 1];
            float q2 = csr_val[e + 2], q3 = csr_val[e + 3];
            const float4* r0 = in4 + s0 * R4;
            const float4* r1 = in4 + s1 * R4;
            const float4* r2 = in4 + s2 * R4;
            const float4* r3 = in4 + s3 * R4;
            float4 u0 = r0[c0], v0 = r0[c1r];
            float4 u1 = r1[c0], v1 = r1[c1r];
            float4 u2 = r2[c0], v2 = r2[c1r];
            float4 u3 = r3[c0], v3 = r3[c1r];
            ax0 = fmaf(q0, u0.x, ax0); ay0 = fmaf(q0, u0.y, ay0);
            az0 = fmaf(q0, u0.z, az0); aw0 = fmaf(q0, u0.w, aw0);
            ax1 = fmaf(q0, v0.x, ax1); ay1 = fmaf(q0, v0.y, ay1);
            az1 = fmaf(q0, v0.z, az1); aw1 = fmaf(q0, v0.w, aw1);
            ax0 = fmaf(q1, u1.x, ax0); ay0 = fmaf(q1, u1.y, ay0);
            az0 = fmaf(q1, u1.z, az0); aw0 = fmaf(q1, u1.w, aw0);
            ax1 = fmaf(q1, v1.x, ax1); ay1 = fmaf(q1, v1.y, ay1);
            az1 = fmaf(q1, v1.z, az1); aw1 = fmaf(q1, v1.w, aw1);
            ax0 = fmaf(q2, u2.x, ax0); ay0 = fmaf(q2, u2.y, ay0);
            az0 = fmaf(q2, u2.z, az0); aw0 = fmaf(q2, u2.w, aw0);
            ax1 = fmaf(q2, v2.x, ax1); ay1 = fmaf(q2, v2.y, ay1);
            az1 = fmaf(q2, v2.z, az1); aw1 = fmaf(q2, v2.w, aw1);
            ax0 = fmaf(q3, u3.x, ax0); ay0 = fmaf(q3, u3.y, ay0);
            az0 = fmaf(q3, u3.z, az0); aw0 = fmaf(q3, u3.w, aw0);
            ax1 = fmaf(q3, v3.x, ax1); ay1 = fmaf(q3, v3.y, ay1);
            az1 = fmaf(q3, v3.z, az1); aw1 = fmaf(q3, v3.w, aw1);
        }
        for (; e < end; ++e) {
            int s = csr_src[e];
            float q = csr_val[e];
            const float4* r = in4 + s * R4;
            float4 u = r[c0], v = r[c1r];
            ax0 = fmaf(q, u.x, ax0); ay0 = fmaf(q, u.y, ay0);
            az0 = fmaf(q, u.z, az0); aw0 = fmaf(q, u.w, aw0);
            ax1 = fmaf(q, v.x, ax1); ay1 = fmaf(q, v.y, ay1);
            az1 = fmaf(q, v.z, az1); aw1 = fmaf(q, v.w, aw1);
        }
        float sn = nrm[n];
        float4 o0 = { ax0 * sn, ay0 * sn, az0 * sn, aw0 * sn };
        out4[n * R4 + c0] = o0;
        if (has2) {
            float4 o1 = { ax1 * sn, ay1 * sn, az1 * sn, aw1 * sn };
            out4[n * R4 + c1] = o1;
        }
    }
}

// ---------------- one feats-block of the dense matmul on MFMA --------------
template<int D_IN, int D_OUT, int KT, int NT, int WOFF_U32>
__device__ __forceinline__ void dense_block(const float* __restrict__ buf, int b,
                                            int mt, int lane, f32x4 (&acc)[NT]) {
    int row = mt * 16 + (lane & 15);
    row = row > NODES - 1 ? NODES - 1 : row;   // clamped rows masked at store
    const float* __restrict__ hrow = buf + row * STRIDE;
    const int kg = (lane >> 4) << 2;
    const uint4* __restrict__ wb =
        (const uint4*)(g_packW + WOFF_U32) + b * (KT * NT * 128) + lane * 2;
    // full unroll: whole b-block is one BB; with the 128-VGPR budget (R14)
    // the scheduler can now hoist next-kt h4/B loads under current MFMAs.
#pragma unroll
    for (int kt = 0; kt < KT; ++kt) {
        // clamp so reads stay inside the row's 76 valid floats (finite data;
        // k>=D_IN lanes are killed by zeroed W rows, value irrelevant).
        int o0 = kt * 32 + kg;      if (o0 > 72) o0 = 72;
        int o1 = kt * 32 + 16 + kg; if (o1 > 72) o1 = 72;
        const float4 f0 = *(const float4*)(hrow + o0);   // ds_read_b128
        const float4 f1 = *(const float4*)(hrow + o1);
        FragU Ah, Al;
        split_pair(f0.x, f0.y, Ah.u[0], Al.u[0]);
        split_pair(f0.z, f0.w, Ah.u[1], Al.u[1]);
        split_pair(f1.x, f1.y, Ah.u[2], Al.u[2]);
        split_pair(f1.z, f1.w, Ah.u[3], Al.u[3]);
#pragma unroll
        for (int nt = 0; nt < NT; ++nt) {
            const uint4* __restrict__ wl = wb + (kt * NT + nt) * 128;
            FragU Bh, Bl;
            Bh.q = wl[0];            // global_load_dwordx4, L1/L2-resident
            Bl.q = wl[1];
            acc[nt] = __builtin_amdgcn_mfma_f32_16x16x32_bf16(Ah.s, Bh.s, acc[nt], 0, 0, 0);
            acc[nt] = __builtin_amdgcn_mfma_f32_16x16x32_bf16(Ah.s, Bl.s, acc[nt], 0, 0, 0);
            acc[nt] = __builtin_amdgcn_mfma_f32_16x16x32_bf16(Al.s, Bh.s, acc[nt], 0, 0, 0);
        }
    }
}

// ---------------- one TAGConv layer (src S, output -> T) -------------------
// Phase 1: gblock(S,0) || prop(S->T); B. Phase 2: gblock(T,1) || prop(T->S); B.
// Phase 3: gblock(S,2); store ReLU -> T (T dead after phase 2; nothing reads
// T in phase 3, so no barrier between gblock2 and store). B. Next src = T.
// Stale cols >= D_OUT in T are killed by zero-padded W / never read by gate.
template<int D_IN, int D_OUT, int KT, int NT, int WOFF_U32>
__device__ __forceinline__ void tag_layer(Smem& sm,
                                          float* __restrict__ S,
                                          float* __restrict__ T,
                                          const float* __restrict__ Bv,
                                          int tid)
{
    const int wave  = __builtin_amdgcn_readfirstlane(tid >> 6); // uniform
    const int lane  = tid & 63;
    const bool m_act = wave < 7;      // 7 m-tiles cover 100 rows; wave7 prop-only

    f32x4 acc[NT];
#pragma unroll
    for (int nt = 0; nt < NT; ++nt) acc[nt] = (f32x4)(0.f);

    if (m_act) dense_block<D_IN, D_OUT, KT, NT, WOFF_U32>(S, 0, wave, lane, acc);
    propagate<D_IN>(S, T, sm.csr_src, sm.csr_val, sm.row_start, sm.nrm, wave, lane);
    __syncthreads();
    if (m_act) dense_block<D_IN, D_OUT, KT, NT, WOFF_U32>(T, 1, wave, lane, acc);
    propagate<D_IN>(T, S, sm.csr_src, sm.csr_val, sm.row_start, sm.nrm, wave, lane);
    __syncthreads();
    if (m_act) {
        dense_block<D_IN, D_OUT, KT, NT, WOFF_U32>(S, 2, wave, lane, acc);
        // C/D layout (verified): col = lane&15, row_in_tile = (lane>>4)*4 + r
#pragma unroll
        for (int nt = 0; nt < NT; ++nt) {
            int col = nt * 16 + (lane & 15);
            if (col < D_OUT) {
                float bias = Bv[col];
#pragma unroll
                for (int r = 0; r < 4; ++r) {
                    int row = wave * 16 + ((lane >> 4) << 2) + r;
                    if (row < NODES)
                        T[row * STRIDE + col] = fmaxf(acc[nt][r] + bias, 0.f);
                }
            }
        }
    }
    __syncthreads();
}

// (512,2): VGPR cap 128. Residency needs only <=128 (16 waves/CU, LDS-bound
// at 2 blocks). The old (512,4) cap of 64 forced the 52-VGPR tight schedule
// that defeated R8/R10's load hoisting.
__global__ __launch_bounds__(NTHR, 2)
void drug_graph_conv_kernel(
    const float* __restrict__ x,
    const int*   __restrict__ src,
    const int*   __restrict__ dst,
    const float* __restrict__ b0, const float* __restrict__ b1,
    const float* __restrict__ b2, const float* __restrict__ b3,
    const float* __restrict__ b4,
    const float* __restrict__ gate_w, const float* __restrict__ gate_b,
    float* __restrict__ out)
{
    __shared__ Smem sm;
    const int g     = blockIdx.x;
    const int tid   = threadIdx.x;
    const int nbase = g * NODES;

    // ---- stage x (100 x 74) into bufA at stride 76, dwordx4 loads ----
    {
        const float4* __restrict__ x4 = (const float4*)(x + (size_t)nbase * 74);
        for (int t = tid; t < NODES * 74 / 4; t += NTHR) {   // 1850
            float4 v = x4[t];
            int idx = 4 * t;
#pragma unroll
            for (int k = 0; k < 4; ++k) {
                int ik = idx + k;
                int n  = ik / 74;
                int d  = ik - n * 74;
                float val = (k == 0) ? v.x : (k == 1) ? v.y : (k == 2) ? v.z : v.w;
                sm.bufA[n * STRIDE + d] = val;
            }
        }
    }
    for (int t = tid; t < NODES * 2; t += NTHR) {
        int n = t >> 1;
        sm.bufA[n * STRIDE + 74 + (t & 1)] = 0.f;
    }

    // ---- degree count ----
    if (tid < NODES) sm.cntg[tid] = 0;
    __syncthreads();
    int es = 0, ed = 0;
    const bool ethr = tid < EDGES;
    if (ethr) {
        es = src[g * EDGES + tid] - nbase;
        ed = dst[g * EDGES + tid] - nbase;
        atomicAdd(&sm.cntg[ed], 1);
    }
    __syncthreads();

    // ---- norm + CSR row offsets (wave-0 shuffle scan over 100 degrees) ----
    if (tid < NODES) sm.nrm[tid] = rsqrtf((float)max(sm.cntg[tid], 1));
    if (tid < 64) {
        int v1 = (tid < NODES) ? sm.cntg[tid] : 0;
        int l2 = tid + 64;
        int v2 = (l2 < NODES) ? sm.cntg[l2] : 0;
        int s1 = v1;
#pragma unroll
        for (int d = 1; d < 64; d <<= 1) {
            int t2 = __shfl_up(s1, d, 64);
            if (tid >= d) s1 += t2;
        }
        int tot1 = __shfl(s1, 63, 64);
        int s2 = v2;
#pragma unroll
        for (int d = 1; d < 64; d <<= 1) {
            int t2 = __shfl_up(s2, d, 64);
            if (tid >= d) s2 += t2;
        }
        s2 += tot1;
        if (tid == 0) sm.row_start[0] = 0;
        sm.row_start[tid + 1] = s1;
        if (l2 < NODES) sm.row_start[l2 + 1] = s2;
    }
    __syncthreads();
    if (tid < NODES) sm.cntg[tid] = 0;   // reuse as CSR fill cursor
    __syncthreads();
    if (ethr) {
        int pos = atomicAdd(&sm.cntg[ed], 1);
        int slot = sm.row_start[ed] + pos;
        sm.csr_src[slot] = (unsigned short)es;
        sm.csr_val[slot] = sm.nrm[es];
    }
    __syncthreads();

    // ---- 5 TAGConv layers (MFMA dense), src/dst buffers alternate ----
    tag_layer<74, 70, 3, 5,     0>(sm, sm.bufA, sm.bufB, b0, tid);
    tag_layer<70, 65, 3, 5, 23040>(sm, sm.bufB, sm.bufA, b1, tid);
    tag_layer<65, 60, 3, 4, 46080>(sm, sm.bufA, sm.bufB, b2, tid);
    tag_layer<60, 55, 2, 4, 64512>(sm, sm.bufB, sm.bufA, b3, tid);
    tag_layer<55, 37, 2, 3, 76800>(sm, sm.bufA, sm.bufB, b4, tid);
    // final h: 100 x 37 in bufB, stride 76

    // ---- gate + softmax + pool (gate stored in cntg as float) ----
    float* gate = (float*)sm.cntg;
    if (tid < NODES) {
        float s = gate_b[0];
#pragma unroll
        for (int k = 0; k < 37; ++k)
            s = fmaf(sm.bufB[tid * STRIDE + k], gate_w[k], s);
        gate[tid] = s;
    }
    __syncthreads();
    if (tid < 64) {
        float v1 = (tid < NODES) ? gate[tid] : -INFINITY;
        float v2 = (tid + 64 < NODES) ? gate[tid + 64] : -INFINITY;
        float m = fmaxf(v1, v2);
#pragma unroll
        for (int d = 32; d; d >>= 1) m = fmaxf(m, __shfl_xor(m, d, 64));
        float e1 = (tid < NODES) ? __expf(v1 - m) : 0.f;
        float e2 = (tid + 64 < NODES) ? __expf(v2 - m) : 0.f;
        float z = e1 + e2;
#pragma unroll
        for (int d = 32; d; d >>= 1) z += __shfl_xor(z, d, 64);
        float inv = 1.f / z;
        if (tid < NODES) gate[tid] = e1 * inv;
        if (tid + 64 < NODES) gate[tid + 64] = e2 * inv;
    }
    __syncthreads();

    // ---- parallel pool: 8 waves x 37 cols, partials in csr_val scratch ----
    {
        const int w = tid >> 6, l = tid & 63;
        if (l < 37) {
            float p = 0.f;
            for (int n = w; n < NODES; n += 8)
                p = fmaf(gate[n], sm.bufB[n * STRIDE + l], p);
            sm.csr_val[w * 37 + l] = p;
        }
    }
    __syncthreads();
    if (tid < 37) {
        float p = 0.f;
#pragma unroll
        for (int w = 0; w < 8; ++w) p += sm.csr_val[w * 37 + tid];
        out[g * 37 + tid] = p;
    }
}

extern "C" void kernel_launch(void* const* d_in, const int* in_sizes, int n_in,
                              void* d_out, int out_size, void* d_ws, size_t ws_size,
                              hipStream_t stream) {
    const float* x   = (const float*)d_in[0];
    const int*   src = (const int*)  d_in[1];
    const int*   dst = (const int*)  d_in[2];
    // d_in[3] = graph_ids (implicit: node / 100) -- unused
    const float* W0 = (const float*)d_in[4];  const float* b0 = (const float*)d_in[5];
    const float* W1 = (const float*)d_in[6];  const float* b1 = (const float*)d_in[7];
    const float* W2 = (const float*)d_in[8];  const float* b2 = (const float*)d_in[9];
    const float* W3 = (const float*)d_in[10]; const float* b3 = (const float*)d_in[11];
    const float* W4 = (const float*)d_in[12]; const float* b4 = (const float*)d_in[13];
    const float* gw = (const float*)d_in[14]; const float* gb = (const float*)d_in[15];
    float* out = (float*)d_out;

    // repack W into MFMA frag layout (max layer 45 tiles * 64 = 2880 thr)
    dim3 rg(12, 5, 1);
    repack_kernel<<<rg, 256, 0, stream>>>(W0, W1, W2, W3, W4);

    drug_graph_conv_kernel<<<5000, NTHR, 0, stream>>>(
        x, src, dst, b0, b1, b2, b3, b4, gw, gb, out);
}

// Round 9
// 771.094 us; speedup vs baseline: 1.4228x; 1.0474x over previous
//
#include <hip/hip_runtime.h>
#include <math.h>

// DrugGraphConv: 5000 graphs x 100 nodes x 400 edges, 5 TAGConv(K=2) layers
// DIMS = [74,70,65,60,55,37], gated softmax pooling per graph.
//
// R9 (732us): dense on MFMA bf16 hi/lo split (AhBh+AhBl+AlBh).
// R10 (701us): buffer-flip layer output, x dwordx4 staging, full kt unroll.
// R11 (690us): dual-chunk propagate + weighted wave shares (conflicts +55%).
// R12/R13: 1024-thr dead (spills / lost co-residency / worse barrier domain).
// R14 (689us): VGPR cap 128 -> compiler STILL picks 52; schedule is its
// choice, not budget-forced. Source-level scheduling levers exhausted.
//
// R15: propagate only (largest VALU consumer):
// (a) degree-sorted task order via LDS counting sort (order[] rank->node):
//     a wave-iter's lanes get ~equal edge-loop trips -> exec-mask waste
//     ~2x -> ~1.1x. Wave assignment block-cyclic over 9 slots (wave 7 owns
//     slots 7+8) to rebalance after sorting.
// (b) split-halves chunk pairing (c0=p, c1=p+PR) instead of (2p,2p+1):
//     consecutive lanes differ by +16B (+4 banks) again -> undoes R11's
//     bank-conflict regression at identical coverage.
// No numerics change: per-node accumulation order is untouched.

typedef __attribute__((ext_vector_type(8))) short bf16x8;
typedef __attribute__((ext_vector_type(4))) float f32x4;

constexpr int NODES  = 100;
constexpr int EDGES  = 400;
constexpr int STRIDE = 76;     // floats per LDS row (mult of 4; 76%32=12 ->
                               // random-row gathers span 8 bank groups)
constexpr int NTHR   = 512;

// packed W frags: per layer, per (b,kt,nt): 64 lanes x (8 bf16 hi + 8 bf16 lo)
// = 2048B per frag-tile. tiles: L0 3*3*5=45, L1 45, L2 36, L3 24, L4 18.
// u32 offsets: 0, 23040, 46080, 64512, 76800; total 86016 u32 = 344KB.
__device__ __align__(16) unsigned g_packW[86016];

struct __align__(16) Smem {
    float bufA[NODES * STRIDE];        // 30,400 B
    float bufB[NODES * STRIDE];        // 30,400 B
    float csr_val[EDGES];              //  1,600 B (nrm[src]; pool scratch later)
    unsigned short csr_src[EDGES];     //    800 B
    int   row_start[NODES + 1];        //    404 B
    int   cntg[NODES];                 //    400 B (cnt setup, gate after)
    float nrm[NODES];                  //    400 B
    int   hist[64];                    //    256 B (deg histogram / cursor)
    unsigned short order[NODES];       //    200 B (deg-sorted rank -> node)
};                                     // => 64,860 B; 2 blocks = 129,720
                                       //    <= 163,840 (160KB/CU) -> 2 blocks/CU

union FragU { unsigned u[4]; uint4 q; bf16x8 s; };

// truncation hi/lo bf16 split of a pair, packed little-endian (a -> low16).
__device__ __forceinline__ void split_pair(float a, float b,
                                           unsigned& h, unsigned& l) {
    unsigned ua = __float_as_uint(a), ub = __float_as_uint(b);
    unsigned ha = ua & 0xFFFF0000u,  hb = ub & 0xFFFF0000u;
    h = (ua >> 16) | hb;
    float ra = a - __uint_as_float(ha);
    float rb = b - __uint_as_float(hb);
    l = (__float_as_uint(ra) >> 16) | (__float_as_uint(rb) & 0xFFFF0000u);
}

// ---------------- repack kernel: W -> frag-ready bf16 hi/lo ----------------
template<int D_IN, int D_OUT, int KT, int NT, int WOFF_U32>
__device__ __forceinline__ void repack_layer(const float* __restrict__ W, int idx) {
    constexpr int TILES = 3 * KT * NT;
    if (idx >= TILES * 64) return;
    int lane = idx & 63, tile = idx >> 6;
    int nt = tile % NT;
    int kt = (tile / NT) % KT;
    int b  = tile / (NT * KT);
    int col = nt * 16 + (lane & 15);
    int kg  = (lane >> 4) << 2;
    float v[8];
#pragma unroll
    for (int i = 0; i < 8; ++i) {
        int k = kt * 32 + ((i >= 4) ? 16 : 0) + kg + (i & 3);
        float f = 0.f;
        if (k < D_IN && col < D_OUT) f = W[(b * D_IN + k) * D_OUT + col];
        v[i] = f;
    }
    unsigned hu[4], lu[4];
#pragma unroll
    for (int p = 0; p < 4; ++p) split_pair(v[2*p], v[2*p+1], hu[p], lu[p]);
    unsigned* dst = g_packW + WOFF_U32 + (tile * 64 + lane) * 8;
    *(uint4*)(dst)     = make_uint4(hu[0], hu[1], hu[2], hu[3]);
    *(uint4*)(dst + 4) = make_uint4(lu[0], lu[1], lu[2], lu[3]);
}

__global__ void repack_kernel(const float* __restrict__ W0, const float* __restrict__ W1,
                              const float* __restrict__ W2, const float* __restrict__ W3,
                              const float* __restrict__ W4) {
    int idx = blockIdx.x * 256 + threadIdx.x;
    switch (blockIdx.y) {
    case 0: repack_layer<74, 70, 3, 5,     0>(W0, idx); break;
    case 1: repack_layer<70, 65, 3, 5, 23040>(W1, idx); break;
    case 2: repack_layer<65, 60, 3, 4, 46080>(W2, idx); break;
    case 3: repack_layer<60, 55, 2, 4, 64512>(W3, idx); break;
    case 4: repack_layer<55, 37, 2, 3, 76800>(W4, idx); break;
    }
}

// ---------------- propagation (CSR gather, fp32 VALU) ----------------------
// out[n][:] = nrm[n] * sum_{e: dst==n} csr_val[e] * in[src_e][:]
// Tasks walk deg-sorted node order; chunk pair = (p, p+PR) (split halves).
// Wave w<7 does blocks {w, w+9, ...}; wave 7 does {7,8, 16,17, ...}.
template<int D_IN>
__device__ __forceinline__ void propagate(const float* __restrict__ in,
                                          float* __restrict__ outb,
                                          const unsigned short* __restrict__ csr_src,
                                          const float* __restrict__ csr_val,
                                          const int* __restrict__ row_start,
                                          const float* __restrict__ nrm,
                                          const unsigned short* __restrict__ order,
                                          int wave, int lane)
{
    constexpr int CH = (D_IN + 3) / 4;            // valid float4 chunks
    constexpr int PR = (CH + 1) / 2;              // chunk-pairs per node
    constexpr int T  = NODES * PR;                // total tasks
    constexpr int NB = (T + 63) / 64;             // 64-task blocks
    constexpr int R4 = STRIDE / 4;                // 19 float4 per row
    const float4* __restrict__ in4 = (const float4*)in;
    float4* __restrict__ out4 = (float4*)outb;

    auto do_block = [&](int j) {
        int t = (j << 6) + lane;
        if (t >= T) return;
        int r = t / PR;                           // sorted rank (const-div)
        int p = t - r * PR;
        int n = order[r];                         // LDS broadcast (PR lanes share)
        int c0 = p;
        int c1 = p + PR;
        bool has2 = (c1 < CH);
        int c1r = has2 ? c1 : c0;                 // safe read index
        int beg = row_start[n], end = row_start[n + 1];
        float ax0 = 0.f, ay0 = 0.f, az0 = 0.f, aw0 = 0.f;
        float ax1 = 0.f, ay1 = 0.f, az1 = 0.f, aw1 = 0.f;
        int e = beg;
        for (; e + 3 < end; e += 4) {
            int   s0 = csr_src[e],     s1 = csr_src[e + 1];
            int   s2 = csr_src[e + 2], s3 = csr_src[e + 3];
            float q0 = csr_val[e],     q1 = csr_val[e + 1];
            float q2 = csr_val[e + 2], q3 = csr_val[e + 3];
            const float4* r0 = in4 + s0 * R4;
            const float4* r1 = in4 + s1 * R4;
            const float4* r2 = in4 + s2 * R4;
            const float4* r3 = in4 + s3 * R4;
            float4 u0 = r0[c0], v0 = r0[c1r];
            float4 u1 = r1[c0], v1 = r1[c1r];
            float4 u2 = r2[c0], v2 = r2[c1r];
            float4 u3 = r3[c0], v3 = r3[c1r];
            ax0 = fmaf(q0, u0.x, ax0); ay0 = fmaf(q0, u0.y, ay0);
            az0 = fmaf(q0, u0.z, az0); aw0 = fmaf(q0, u0.w, aw0);
            ax1 = fmaf(q0, v0.x, ax1); ay1 = fmaf(q0, v0.y, ay1);
            az1 = fmaf(q0, v0.z, az1); aw1 = fmaf(q0, v0.w, aw1);
            ax0 = fmaf(q1, u1.x, ax0); ay0 = fmaf(q1, u1.y, ay0);
            az0 = fmaf(q1, u1.z, az0); aw0 = fmaf(q1, u1.w, aw0);
            ax1 = fmaf(q1, v1.x, ax1); ay1 = fmaf(q1, v1.y, ay1);
            az1 = fmaf(q1, v1.z, az1); aw1 = fmaf(q1, v1.w, aw1);
            ax0 = fmaf(q2, u2.x, ax0); ay0 = fmaf(q2, u2.y, ay0);
            az0 = fmaf(q2, u2.z, az0); aw0 = fmaf(q2, u2.w, aw0);
            ax1 = fmaf(q2, v2.x, ax1); ay1 = fmaf(q2, v2.y, ay1);
            az1 = fmaf(q2, v2.z, az1); aw1 = fmaf(q2, v2.w, aw1);
            ax0 = fmaf(q3, u3.x, ax0); ay0 = fmaf(q3, u3.y, ay0);
            az0 = fmaf(q3, u3.z, az0); aw0 = fmaf(q3, u3.w, aw0);
            ax1 = fmaf(q3, v3.x, ax1); ay1 = fmaf(q3, v3.y, ay1);
            az1 = fmaf(q3, v3.z, az1); aw1 = fmaf(q3, v3.w, aw1);
        }
        for (; e < end; ++e) {
            int s = csr_src[e];
            float q = csr_val[e];
            const float4* rr = in4 + s * R4;
            float4 u = rr[c0], v = rr[c1r];
            ax0 = fmaf(q, u.x, ax0); ay0 = fmaf(q, u.y, ay0);
            az0 = fmaf(q, u.z, az0); aw0 = fmaf(q, u.w, aw0);
            ax1 = fmaf(q, v.x, ax1); ay1 = fmaf(q, v.y, ay1);
            az1 = fmaf(q, v.z, az1); aw1 = fmaf(q, v.w, aw1);
        }
        float sn = nrm[n];
        float4 o0 = { ax0 * sn, ay0 * sn, az0 * sn, aw0 * sn };
        out4[n * R4 + c0] = o0;
        if (has2) {
            float4 o1 = { ax1 * sn, ay1 * sn, az1 * sn, aw1 * sn };
            out4[n * R4 + c1] = o1;
        }
    };

    if (wave < 7) {
        for (int j = wave; j < NB; j += 9) do_block(j);
    } else {
        for (int j = 7; j < NB; j += 9) do_block(j);
        for (int j = 8; j < NB; j += 9) do_block(j);
    }
}

// ---------------- one feats-block of the dense matmul on MFMA --------------
template<int D_IN, int D_OUT, int KT, int NT, int WOFF_U32>
__device__ __forceinline__ void dense_block(const float* __restrict__ buf, int b,
                                            int mt, int lane, f32x4 (&acc)[NT]) {
    int row = mt * 16 + (lane & 15);
    row = row > NODES - 1 ? NODES - 1 : row;   // clamped rows masked at store
    const float* __restrict__ hrow = buf + row * STRIDE;
    const int kg = (lane >> 4) << 2;
    const uint4* __restrict__ wb =
        (const uint4*)(g_packW + WOFF_U32) + b * (KT * NT * 128) + lane * 2;
#pragma unroll
    for (int kt = 0; kt < KT; ++kt) {
        // clamp so reads stay inside the row's 76 valid floats (finite data;
        // k>=D_IN lanes are killed by zeroed W rows, value irrelevant).
        int o0 = kt * 32 + kg;      if (o0 > 72) o0 = 72;
        int o1 = kt * 32 + 16 + kg; if (o1 > 72) o1 = 72;
        const float4 f0 = *(const float4*)(hrow + o0);   // ds_read_b128
        const float4 f1 = *(const float4*)(hrow + o1);
        FragU Ah, Al;
        split_pair(f0.x, f0.y, Ah.u[0], Al.u[0]);
        split_pair(f0.z, f0.w, Ah.u[1], Al.u[1]);
        split_pair(f1.x, f1.y, Ah.u[2], Al.u[2]);
        split_pair(f1.z, f1.w, Ah.u[3], Al.u[3]);
#pragma unroll
        for (int nt = 0; nt < NT; ++nt) {
            const uint4* __restrict__ wl = wb + (kt * NT + nt) * 128;
            FragU Bh, Bl;
            Bh.q = wl[0];            // global_load_dwordx4, L1/L2-resident
            Bl.q = wl[1];
            acc[nt] = __builtin_amdgcn_mfma_f32_16x16x32_bf16(Ah.s, Bh.s, acc[nt], 0, 0, 0);
            acc[nt] = __builtin_amdgcn_mfma_f32_16x16x32_bf16(Ah.s, Bl.s, acc[nt], 0, 0, 0);
            acc[nt] = __builtin_amdgcn_mfma_f32_16x16x32_bf16(Al.s, Bh.s, acc[nt], 0, 0, 0);
        }
    }
}

// ---------------- one TAGConv layer (src S, output -> T) -------------------
// Phase 1: gblock(S,0) || prop(S->T); B. Phase 2: gblock(T,1) || prop(T->S); B.
// Phase 3: gblock(S,2); store ReLU -> T (T dead after phase 2; nothing reads
// T in phase 3, so no barrier between gblock2 and store). B. Next src = T.
// Stale cols >= D_OUT in T are killed by zero-padded W / never read by gate.
template<int D_IN, int D_OUT, int KT, int NT, int WOFF_U32>
__device__ __forceinline__ void tag_layer(Smem& sm,
                                          float* __restrict__ S,
                                          float* __restrict__ T,
                                          const float* __restrict__ Bv,
                                          int tid)
{
    const int wave  = __builtin_amdgcn_readfirstlane(tid >> 6); // uniform
    const int lane  = tid & 63;
    const bool m_act = wave < 7;      // 7 m-tiles cover 100 rows; wave7 prop-heavy

    f32x4 acc[NT];
#pragma unroll
    for (int nt = 0; nt < NT; ++nt) acc[nt] = (f32x4)(0.f);

    if (m_act) dense_block<D_IN, D_OUT, KT, NT, WOFF_U32>(S, 0, wave, lane, acc);
    propagate<D_IN>(S, T, sm.csr_src, sm.csr_val, sm.row_start, sm.nrm,
                    sm.order, wave, lane);
    __syncthreads();
    if (m_act) dense_block<D_IN, D_OUT, KT, NT, WOFF_U32>(T, 1, wave, lane, acc);
    propagate<D_IN>(T, S, sm.csr_src, sm.csr_val, sm.row_start, sm.nrm,
                    sm.order, wave, lane);
    __syncthreads();
    if (m_act) {
        dense_block<D_IN, D_OUT, KT, NT, WOFF_U32>(S, 2, wave, lane, acc);
        // C/D layout (verified): col = lane&15, row_in_tile = (lane>>4)*4 + r
#pragma unroll
        for (int nt = 0; nt < NT; ++nt) {
            int col = nt * 16 + (lane & 15);
            if (col < D_OUT) {
                float bias = Bv[col];
#pragma unroll
                for (int r = 0; r < 4; ++r) {
                    int row = wave * 16 + ((lane >> 4) << 2) + r;
                    if (row < NODES)
                        T[row * STRIDE + col] = fmaxf(acc[nt][r] + bias, 0.f);
                }
            }
        }
    }
    __syncthreads();
}

// (512,2): VGPR cap 128 (compiler settles ~52; residency is LDS-bound at 2
// blocks/CU = 16 waves regardless).
__global__ __launch_bounds__(NTHR, 2)
void drug_graph_conv_kernel(
    const float* __restrict__ x,
    const int*   __restrict__ src,
    const int*   __restrict__ dst,
    const float* __restrict__ b0, const float* __restrict__ b1,
    const float* __restrict__ b2, const float* __restrict__ b3,
    const float* __restrict__ b4,
    const float* __restrict__ gate_w, const float* __restrict__ gate_b,
    float* __restrict__ out)
{
    __shared__ Smem sm;
    const int g     = blockIdx.x;
    const int tid   = threadIdx.x;
    const int nbase = g * NODES;

    // ---- stage x (100 x 74) into bufA at stride 76, dwordx4 loads ----
    {
        const float4* __restrict__ x4 = (const float4*)(x + (size_t)nbase * 74);
        for (int t = tid; t < NODES * 74 / 4; t += NTHR) {   // 1850
            float4 v = x4[t];
            int idx = 4 * t;
#pragma unroll
            for (int k = 0; k < 4; ++k) {
                int ik = idx + k;
                int n  = ik / 74;
                int d  = ik - n * 74;
                float val = (k == 0) ? v.x : (k == 1) ? v.y : (k == 2) ? v.z : v.w;
                sm.bufA[n * STRIDE + d] = val;
            }
        }
    }
    for (int t = tid; t < NODES * 2; t += NTHR) {
        int n = t >> 1;
        sm.bufA[n * STRIDE + 74 + (t & 1)] = 0.f;
    }

    // ---- degree count ----
    if (tid < NODES) sm.cntg[tid] = 0;
    __syncthreads();
    int es = 0, ed = 0;
    const bool ethr = tid < EDGES;
    if (ethr) {
        es = src[g * EDGES + tid] - nbase;
        ed = dst[g * EDGES + tid] - nbase;
        atomicAdd(&sm.cntg[ed], 1);
    }
    __syncthreads();

    // ---- norm + CSR row offsets (wave-0 shuffle scan); zero hist (wave 2) --
    if (tid < NODES) sm.nrm[tid] = rsqrtf((float)max(sm.cntg[tid], 1));
    if (tid >= 128 && tid < 192) sm.hist[tid - 128] = 0;
    if (tid < 64) {
        int v1 = (tid < NODES) ? sm.cntg[tid] : 0;
        int l2 = tid + 64;
        int v2 = (l2 < NODES) ? sm.cntg[l2] : 0;
        int s1 = v1;
#pragma unroll
        for (int d = 1; d < 64; d <<= 1) {
            int t2 = __shfl_up(s1, d, 64);
            if (tid >= d) s1 += t2;
        }
        int tot1 = __shfl(s1, 63, 64);
        int s2 = v2;
#pragma unroll
        for (int d = 1; d < 64; d <<= 1) {
            int t2 = __shfl_up(s2, d, 64);
            if (tid >= d) s2 += t2;
        }
        s2 += tot1;
        if (tid == 0) sm.row_start[0] = 0;
        sm.row_start[tid + 1] = s1;
        if (l2 < NODES) sm.row_start[l2 + 1] = s2;
    }
    __syncthreads();

    // ---- counting sort of nodes by degree -> order[] (rank -> node id) ----
    if (tid < NODES) atomicAdd(&sm.hist[min(sm.cntg[tid], 63)], 1);
    __syncthreads();
    if (tid < 64) {                       // exclusive scan of 64 bins
        int v = sm.hist[tid];
        int s = v;
#pragma unroll
        for (int d = 1; d < 64; d <<= 1) {
            int t2 = __shfl_up(s, d, 64);
            if (tid >= d) s += t2;
        }
        sm.hist[tid] = s - v;
    }
    __syncthreads();
    if (tid < NODES) {
        int pos = atomicAdd(&sm.hist[min(sm.cntg[tid], 63)], 1);
        sm.order[pos] = (unsigned short)tid;
    }
    __syncthreads();

    // ---- CSR fill (cntg reused as cursor) ----
    if (tid < NODES) sm.cntg[tid] = 0;
    __syncthreads();
    if (ethr) {
        int pos = atomicAdd(&sm.cntg[ed], 1);
        int slot = sm.row_start[ed] + pos;
        sm.csr_src[slot] = (unsigned short)es;
        sm.csr_val[slot] = sm.nrm[es];
    }
    __syncthreads();

    // ---- 5 TAGConv layers (MFMA dense), src/dst buffers alternate ----
    tag_layer<74, 70, 3, 5,     0>(sm, sm.bufA, sm.bufB, b0, tid);
    tag_layer<70, 65, 3, 5, 23040>(sm, sm.bufB, sm.bufA, b1, tid);
    tag_layer<65, 60, 3, 4, 46080>(sm, sm.bufA, sm.bufB, b2, tid);
    tag_layer<60, 55, 2, 4, 64512>(sm, sm.bufB, sm.bufA, b3, tid);
    tag_layer<55, 37, 2, 3, 76800>(sm, sm.bufA, sm.bufB, b4, tid);
    // final h: 100 x 37 in bufB, stride 76

    // ---- gate + softmax + pool (gate stored in cntg as float) ----
    float* gate = (float*)sm.cntg;
    if (tid < NODES) {
        float s = gate_b[0];
#pragma unroll
        for (int k = 0; k < 37; ++k)
            s = fmaf(sm.bufB[tid * STRIDE + k], gate_w[k], s);
        gate[tid] = s;
    }
    __syncthreads();
    if (tid < 64) {
        float v1 = (tid < NODES) ? gate[tid] : -INFINITY;
        float v2 = (tid + 64 < NODES) ? gate[tid + 64] : -INFINITY;
        float m = fmaxf(v1, v2);
#pragma unroll
        for (int d = 32; d; d >>= 1) m = fmaxf(m, __shfl_xor(m, d, 64));
        float e1 = (tid < NODES) ? __expf(v1 - m) : 0.f;
        float e2 = (tid + 64 < NODES) ? __expf(v2 - m) : 0.f;
        float z = e1 + e2;
#pragma unroll
        for (int d = 32; d; d >>= 1) z += __shfl_xor(z, d, 64);
        float inv = 1.f / z;
        if (tid < NODES) gate[tid] = e1 * inv;
        if (tid + 64 < NODES) gate[tid + 64] = e2 * inv;
    }
    __syncthreads();

    // ---- parallel pool: 8 waves x 37 cols, partials in csr_val scratch ----
    {
        const int w = tid >> 6, l = tid & 63;
        if (l < 37) {
            float p = 0.f;
            for (int n = w; n < NODES; n += 8)
                p = fmaf(gate[n], sm.bufB[n * STRIDE + l], p);
            sm.csr_val[w * 37 + l] = p;
        }
    }
    __syncthreads();
    if (tid < 37) {
        float p = 0.f;
#pragma unroll
        for (int w = 0; w < 8; ++w) p += sm.csr_val[w * 37 + tid];
        out[g * 37 + tid] = p;
    }
}

extern "C" void kernel_launch(void* const* d_in, const int* in_sizes, int n_in,
                              void* d_out, int out_size, void* d_ws, size_t ws_size,
                              hipStream_t stream) {
    const float* x   = (const float*)d_in[0];
    const int*   src = (const int*)  d_in[1];
    const int*   dst = (const int*)  d_in[2];
    // d_in[3] = graph_ids (implicit: node / 100) -- unused
    const float* W0 = (const float*)d_in[4];  const float* b0 = (const float*)d_in[5];
    const float* W1 = (const float*)d_in[6];  const float* b1 = (const float*)d_in[7];
    const float* W2 = (const float*)d_in[8];  const float* b2 = (const float*)d_in[9];
    const float* W3 = (const float*)d_in[10]; const float* b3 = (const float*)d_in[11];
    const float* W4 = (const float*)d_in[12]; const float* b4 = (const float*)d_in[13];
    const float* gw = (const float*)d_in[14]; const float* gb = (const float*)d_in[15];
    float* out = (float*)d_out;

    // repack W into MFMA frag layout (max layer 45 tiles * 64 = 2880 thr)
    dim3 rg(12, 5, 1);
    repack_kernel<<<rg, 256, 0, stream>>>(W0, W1, W2, W3, W4);

    drug_graph_conv_kernel<<<5000, NTHR, 0, stream>>>(
        x, src, dst, b0, b1, b2, b3, b4, gw, gb, out);
}